// Round 1
// baseline (467.078 us; speedup 1.0000x reference)
//
#include <hip/hip_runtime.h>
#include <math.h>

#define H 256

__device__ __forceinline__ float sigmoidf_(float x) {
    return 1.0f / (1.0f + expf(-x));
}

// ---------------- transpose all weight matrices into workspace ----------------
// Layout in dst (floats): WiT[256*256] WoT WuT UiT[512*256] UoT UuT Uf1T[256*256] Uf2T
// Transposed so that reading across output-index j (threadIdx) is coalesced:
// XT[k*256 + j] = X[j*cols + k]
__global__ __launch_bounds__(256) void transpose_all_kernel(
    const float* __restrict__ Wi, const float* __restrict__ Wo, const float* __restrict__ Wu,
    const float* __restrict__ Ui, const float* __restrict__ Uo, const float* __restrict__ Uu,
    const float* __restrict__ Uf1, const float* __restrict__ Uf2,
    float* __restrict__ dst)
{
    long idx = (long)blockIdx.x * 256 + threadIdx.x;
    const long S = 65536, U2 = 131072;
    const float* src; long cols; long t;
    if      (idx <   S)        { src = Wi;  cols = 256; t = idx; }
    else if (idx < 2*S)        { src = Wo;  cols = 256; t = idx - S; }
    else if (idx < 3*S)        { src = Wu;  cols = 256; t = idx - 2*S; }
    else if (idx < 3*S + U2)   { src = Ui;  cols = 512; t = idx - 3*S; }
    else if (idx < 3*S + 2*U2) { src = Uo;  cols = 512; t = idx - (3*S + U2); }
    else if (idx < 3*S + 3*U2) { src = Uu;  cols = 512; t = idx - (3*S + 2*U2); }
    else if (idx < 4*S + 3*U2) { src = Uf1; cols = 256; t = idx - (3*S + 3*U2); }
    else                       { src = Uf2; cols = 256; t = idx - (4*S + 3*U2); }
    long j = t & 255;
    long k = t >> 8;
    dst[idx] = src[j * cols + k];
}

// ---------------- leaves ----------------
// One block = 256 threads (thread j owns output element j), LPB leaves per block.
// emb reads are wave-uniform (scalar) per leaf; weight reads coalesced across j.
template<int LPB>
__global__ __launch_bounds__(256) void leaf_kernel(
    const int* __restrict__ word_ids, const float* __restrict__ emb,
    const float* __restrict__ WiT, const float* __restrict__ WoT, const float* __restrict__ WuT,
    const float* __restrict__ bi, const float* __restrict__ bo, const float* __restrict__ bu,
    float* __restrict__ h_buf)
{
    const int j = threadIdx.x;
    const int lbase = blockIdx.x * LPB;
    int wid[LPB];
#pragma unroll
    for (int l = 0; l < LPB; ++l)
        wid[l] = __builtin_amdgcn_readfirstlane(word_ids[lbase + l]);

    float ai[LPB], ao[LPB], au[LPB];
#pragma unroll
    for (int l = 0; l < LPB; ++l) { ai[l] = 0.f; ao[l] = 0.f; au[l] = 0.f; }

#pragma unroll 4
    for (int k = 0; k < H; ++k) {
        float wi = WiT[k * H + j];
        float wo = WoT[k * H + j];
        float wu = WuT[k * H + j];
#pragma unroll
        for (int l = 0; l < LPB; ++l) {
            float e = emb[(long)wid[l] * H + k];
            ai[l] = fmaf(e, wi, ai[l]);
            ao[l] = fmaf(e, wo, ao[l]);
            au[l] = fmaf(e, wu, au[l]);
        }
    }
    float bij = bi[j], boj = bo[j], buj = bu[j];
#pragma unroll
    for (int l = 0; l < LPB; ++l) {
        float ii = sigmoidf_(ai[l] + bij);
        float oo = sigmoidf_(ao[l] + boj);
        float uu = fmaxf(au[l] + buj, 0.f);
        float c  = ii * uu;
        float h  = oo * fmaxf(c, 0.f);
        h_buf[(long)(lbase + l) * H + j] = h;
    }
}

// ---------------- one tree level ----------------
// cat = [h[left], h[right]] (512). Gates i,o,u use full cat (UiT/UoT/UuT are 512x256
// transposed); f1 uses left half with Uf1T, f2 right half with Uf2T.
template<int NPB>
__global__ __launch_bounds__(256) void level_kernel(
    const int* __restrict__ left_idx, const int* __restrict__ right_idx,
    const float* __restrict__ UiT, const float* __restrict__ UoT, const float* __restrict__ UuT,
    const float* __restrict__ Uf1T, const float* __restrict__ Uf2T,
    const float* __restrict__ bui, const float* __restrict__ buo, const float* __restrict__ buu,
    const float* __restrict__ bf1, const float* __restrict__ bf2,
    float* __restrict__ h_buf, int level_start, int n_leaves)
{
    const int j = threadIdx.x;
    const int nbase = level_start + blockIdx.x * NPB;

    int li[NPB], ri[NPB];
#pragma unroll
    for (int n = 0; n < NPB; ++n) {
        li[n] = __builtin_amdgcn_readfirstlane(left_idx [nbase + n - n_leaves]);
        ri[n] = __builtin_amdgcn_readfirstlane(right_idx[nbase + n - n_leaves]);
    }

    float ai[NPB], ao[NPB], au[NPB], af1[NPB], af2[NPB];
#pragma unroll
    for (int n = 0; n < NPB; ++n) { ai[n] = ao[n] = au[n] = af1[n] = af2[n] = 0.f; }

    // left half of cat (k = 0..255)
#pragma unroll 4
    for (int k = 0; k < H; ++k) {
        float wi = UiT[k * H + j];
        float wo = UoT[k * H + j];
        float wu = UuT[k * H + j];
        float wf = Uf1T[k * H + j];
#pragma unroll
        for (int n = 0; n < NPB; ++n) {
            float x = h_buf[(long)li[n] * H + k];
            ai[n]  = fmaf(x, wi, ai[n]);
            ao[n]  = fmaf(x, wo, ao[n]);
            au[n]  = fmaf(x, wu, au[n]);
            af1[n] = fmaf(x, wf, af1[n]);
        }
    }
    // right half of cat (k = 256..511)
#pragma unroll 4
    for (int k = 0; k < H; ++k) {
        float wi = UiT[(k + H) * H + j];
        float wo = UoT[(k + H) * H + j];
        float wu = UuT[(k + H) * H + j];
        float wf = Uf2T[k * H + j];
#pragma unroll
        for (int n = 0; n < NPB; ++n) {
            float x = h_buf[(long)ri[n] * H + k];
            ai[n]  = fmaf(x, wi, ai[n]);
            ao[n]  = fmaf(x, wo, ao[n]);
            au[n]  = fmaf(x, wu, au[n]);
            af2[n] = fmaf(x, wf, af2[n]);
        }
    }

    float b1 = bui[j], b2 = buo[j], b3 = buu[j], b4 = bf1[j], b5 = bf2[j];
#pragma unroll
    for (int n = 0; n < NPB; ++n) {
        float lh = h_buf[(long)li[n] * H + j];
        float rh = h_buf[(long)ri[n] * H + j];
        float ii = sigmoidf_(ai[n] + b1);
        float oo = sigmoidf_(ao[n] + b2);
        float uu = fmaxf(au[n] + b3, 0.f);
        float f1 = sigmoidf_(af1[n] + b4);
        float f2 = sigmoidf_(af2[n] + b5);
        float c  = ii * uu + f1 * lh + f2 * rh;
        float h  = oo * fmaxf(c, 0.f);
        h_buf[(long)(nbase + n) * H + j] = h;
    }
}

// ---------------- final projection: logits[node][cls] ----------------
__global__ __launch_bounds__(256) void proj_kernel(
    const float* __restrict__ h_buf, const float* __restrict__ Wp,
    const float* __restrict__ bp, float* __restrict__ out, int total)
{
    int t = blockIdx.x * 256 + threadIdx.x;
    if (t >= total) return;
    int node = t / 5;
    int cls  = t - node * 5;
    const float4* hr = (const float4*)(h_buf + (long)node * H);
    const float4* wr = (const float4*)(Wp + (long)cls * H);
    float acc = 0.f;
#pragma unroll 8
    for (int k = 0; k < H / 4; ++k) {
        float4 a = hr[k], b = wr[k];
        acc += a.x * b.x + a.y * b.y + a.z * b.z + a.w * b.w;
    }
    out[t] = acc + bp[cls];
}

extern "C" void kernel_launch(void* const* d_in, const int* in_sizes, int n_in,
                              void* d_out, int out_size, void* d_ws, size_t ws_size,
                              hipStream_t stream)
{
    const int*   word_ids  = (const int*)  d_in[0];
    const int*   left_idx  = (const int*)  d_in[1];
    const int*   right_idx = (const int*)  d_in[2];
    const float* emb       = (const float*)d_in[3];
    const float* Wi  = (const float*)d_in[4];  const float* bi  = (const float*)d_in[5];
    const float* Wo  = (const float*)d_in[6];  const float* bo  = (const float*)d_in[7];
    const float* Wu  = (const float*)d_in[8];  const float* bu  = (const float*)d_in[9];
    const float* Ui  = (const float*)d_in[10]; const float* bui = (const float*)d_in[11];
    const float* Uo  = (const float*)d_in[12]; const float* buo = (const float*)d_in[13];
    const float* Uu  = (const float*)d_in[14]; const float* buu = (const float*)d_in[15];
    const float* Uf1 = (const float*)d_in[16]; const float* bf1 = (const float*)d_in[17];
    const float* Uf2 = (const float*)d_in[18]; const float* bf2 = (const float*)d_in[19];
    const float* Wp  = (const float*)d_in[20]; const float* bp  = (const float*)d_in[21];

    const int n_leaves   = in_sizes[0];
    const int n_internal = in_sizes[1];
    const int n_nodes    = n_leaves + n_internal;

    // workspace layout (floats)
    float* ws    = (float*)d_ws;
    float* h_buf = ws;                                // [n_nodes][256]
    float* WT    = ws + (long)n_nodes * H;            // transposed weights
    const long S = 65536, U2 = 131072;
    float* WiT  = WT;
    float* WoT  = WiT + S;
    float* WuT  = WoT + S;
    float* UiT  = WuT + S;
    float* UoT  = UiT + U2;
    float* UuT  = UoT + U2;
    float* Uf1T = UuT + U2;
    float* Uf2T = Uf1T + S;
    (void)ws_size; (void)n_in; (void)out_size;

    // 1) transpose weights (720896 elements / 256 = 2816 blocks)
    transpose_all_kernel<<<2816, 256, 0, stream>>>(Wi, Wo, Wu, Ui, Uo, Uu, Uf1, Uf2, WT);

    // 2) leaves
    constexpr int LPB = 4;
    leaf_kernel<LPB><<<n_leaves / LPB, 256, 0, stream>>>(
        word_ids, emb, WiT, WoT, WuT, bi, bo, bu, h_buf);

    // 3) internal levels (stream order enforces level dependency)
    int frontier = n_leaves;
    int node = n_leaves;
    while (frontier > 1) {
        int cnt = frontier >> 1;
        int npb;
        if      ((cnt & 3) == 0 && cnt >= 1024) npb = 4;
        else if ((cnt & 1) == 0 && cnt >= 512)  npb = 2;
        else                                    npb = 1;
        int grid = cnt / npb;
        if (npb == 4)
            level_kernel<4><<<grid, 256, 0, stream>>>(left_idx, right_idx,
                UiT, UoT, UuT, Uf1T, Uf2T, bui, buo, buu, bf1, bf2, h_buf, node, n_leaves);
        else if (npb == 2)
            level_kernel<2><<<grid, 256, 0, stream>>>(left_idx, right_idx,
                UiT, UoT, UuT, Uf1T, Uf2T, bui, buo, buu, bf1, bf2, h_buf, node, n_leaves);
        else
            level_kernel<1><<<grid, 256, 0, stream>>>(left_idx, right_idx,
                UiT, UoT, UuT, Uf1T, Uf2T, bui, buo, buu, bf1, bf2, h_buf, node, n_leaves);
        node += cnt;
        frontier = cnt + (frontier & 1);
    }

    // 4) projection
    int total = n_nodes * 5;
    proj_kernel<<<(total + 255) / 256, 256, 0, stream>>>(h_buf, Wp, bp, (float*)d_out, total);
}

// Round 2
// 300.454 us; speedup vs baseline: 1.5546x; 1.5546x over previous
//
#include <hip/hip_runtime.h>
#include <math.h>

#define H 256
#define KT 32        // k per tile
#define KTILES 16    // 512 / KT

__device__ __forceinline__ float sigmoidf_(float x) {
    return 1.0f / (1.0f + expf(-x));
}

// ---------------- pack weights into workspace ----------------
// W4[g][k][j] for g in {i,o,u,f}, k in [0,512), j in [0,256):
//   g<3 : U_g[j][k]   (transpose of Ui/Uo/Uu, which are [256j][512k] row-major)
//   g=3 : k<256 -> Uf1[j][k], k>=256 -> Uf2[j][k-256]
// Then leaf weights W3[g][k][j] = W_g[j][k] for g in {i,o,u}, k,j in [0,256).
__global__ __launch_bounds__(256) void pack_weights_kernel(
    const float* __restrict__ Wi, const float* __restrict__ Wo, const float* __restrict__ Wu,
    const float* __restrict__ Ui, const float* __restrict__ Uo, const float* __restrict__ Uu,
    const float* __restrict__ Uf1, const float* __restrict__ Uf2,
    float* __restrict__ dst)
{
    long idx = (long)blockIdx.x * 256 + threadIdx.x;
    const long W4N = 4L * 512 * 256;   // 524288
    if (idx < W4N) {
        long g = idx >> 17;            // /131072
        long r = idx & 131071;
        long k = r >> 8;
        long j = r & 255;
        float v;
        if      (g == 0) v = Ui[j * 512 + k];
        else if (g == 1) v = Uo[j * 512 + k];
        else if (g == 2) v = Uu[j * 512 + k];
        else             v = (k < 256) ? Uf1[j * 256 + k] : Uf2[j * 256 + (k - 256)];
        dst[idx] = v;
    } else {
        long t = idx - W4N;
        long g = t >> 16;              // /65536
        long r = t & 65535;
        long k = r >> 8;
        long j = r & 255;
        const float* src = (g == 0) ? Wi : (g == 1) ? Wo : Wu;
        dst[idx] = src[j * 256 + k];
    }
}

// ---------------- leaves ----------------
template<int LPB>
__global__ __launch_bounds__(256) void leaf_kernel(
    const int* __restrict__ word_ids, const float* __restrict__ emb,
    const float* __restrict__ W3,   // [3][256][256] packed (k-major, j coalesced)
    const float* __restrict__ bi, const float* __restrict__ bo, const float* __restrict__ bu,
    float* __restrict__ h_buf)
{
    const int j = threadIdx.x;
    const int lbase = blockIdx.x * LPB;
    int wid[LPB];
#pragma unroll
    for (int l = 0; l < LPB; ++l)
        wid[l] = __builtin_amdgcn_readfirstlane(word_ids[lbase + l]);

    float ai[LPB], ao[LPB], au[LPB];
#pragma unroll
    for (int l = 0; l < LPB; ++l) { ai[l] = 0.f; ao[l] = 0.f; au[l] = 0.f; }

    const float* WiT = W3;
    const float* WoT = W3 + 65536;
    const float* WuT = W3 + 131072;

#pragma unroll 4
    for (int k = 0; k < H; ++k) {
        float wi = WiT[k * H + j];
        float wo = WoT[k * H + j];
        float wu = WuT[k * H + j];
#pragma unroll
        for (int l = 0; l < LPB; ++l) {
            float e = emb[(long)wid[l] * H + k];
            ai[l] = fmaf(e, wi, ai[l]);
            ao[l] = fmaf(e, wo, ao[l]);
            au[l] = fmaf(e, wu, au[l]);
        }
    }
    float bij = bi[j], boj = bo[j], buj = bu[j];
#pragma unroll
    for (int l = 0; l < LPB; ++l) {
        float ii = sigmoidf_(ai[l] + bij);
        float oo = sigmoidf_(ao[l] + boj);
        float uu = fmaxf(au[l] + buj, 0.f);
        float c  = ii * uu;
        float h  = oo * fmaxf(c, 0.f);
        h_buf[(long)(lbase + l) * H + j] = h;
    }
}

// ---------------- level phase A: per-ktile partial matvecs ----------------
// grid = (KTILES, ceil(chunk_nodes/NCH)); block = 256 (thread = output j).
// Block holds its 4x32 weight slice in VGPRs; loops over NCH nodes reading the
// child-h slice via wave-uniform (scalar) loads.
// part layout: part[nc][kt][g][j]  (nc chunk-local), g in {i,o,u,f}.
template<int NCH>
__global__ __launch_bounds__(256) void level_partial_kernel(
    const int* __restrict__ left_idx, const int* __restrict__ right_idx,
    const float* __restrict__ W4, const float* __restrict__ h_buf,
    float* __restrict__ part,
    int level_start, int chunk_base, int chunk_nodes, int n_leaves)
{
    const int j  = threadIdx.x;
    const int kt = blockIdx.x;
    const int nb = blockIdx.y * NCH;

    // load weight slice: w[g][kk] = W4[g][kt*KT + kk][j]
    float w[4][KT];
#pragma unroll
    for (int g = 0; g < 4; ++g)
#pragma unroll
        for (int kk = 0; kk < KT; ++kk)
            w[g][kk] = W4[((long)g * 512 + kt * KT + kk) * H + j];

    const int  isLeft = (kt < 8);
    const int  k0 = (kt & 7) * KT;   // offset within the child's h row
    const int* cidx = isLeft ? left_idx : right_idx;

    const int nEnd = (nb + NCH < chunk_nodes) ? nb + NCH : chunk_nodes;
    for (int n = nb; n < nEnd; ++n) {
        int ti = level_start + chunk_base + n - n_leaves;     // index into left/right arrays
        int child = __builtin_amdgcn_readfirstlane(cidx[ti]);
        const float* row = h_buf + (long)child * H + k0;
        float a0 = 0.f, a1 = 0.f, a2 = 0.f, a3 = 0.f;
#pragma unroll
        for (int kk = 0; kk < KT; ++kk) {
            float x = row[kk];
            a0 = fmaf(x, w[0][kk], a0);
            a1 = fmaf(x, w[1][kk], a1);
            a2 = fmaf(x, w[2][kk], a2);
            a3 = fmaf(x, w[3][kk], a3);
        }
        float* p = part + (((long)n * KTILES + kt) * 4) * H + j;
        p[0]     = a0;
        p[H]     = a1;
        p[2 * H] = a2;
        p[3 * H] = a3;
    }
}

// ---------------- level phase B: reduce partials, apply gates ----------------
// grid = chunk_nodes blocks; block = 256 (thread = j).
__global__ __launch_bounds__(256) void level_reduce_kernel(
    const int* __restrict__ left_idx, const int* __restrict__ right_idx,
    const float* __restrict__ part,
    const float* __restrict__ bui, const float* __restrict__ buo, const float* __restrict__ buu,
    const float* __restrict__ bf1, const float* __restrict__ bf2,
    float* __restrict__ h_buf,
    int level_start, int chunk_base, int n_leaves)
{
    const int j  = threadIdx.x;
    const int nc = blockIdx.x;

    float ai = 0.f, ao = 0.f, au = 0.f, af1 = 0.f, af2 = 0.f;
    const float* p = part + ((long)nc * KTILES * 4) * H + j;
#pragma unroll
    for (int kt = 0; kt < KTILES; ++kt) {
        const float* q = p + (long)kt * 4 * H;
        ai += q[0];
        ao += q[H];
        au += q[2 * H];
        if (kt < 8) af1 += q[3 * H]; else af2 += q[3 * H];
    }

    int node = level_start + chunk_base + nc;
    int ti   = node - n_leaves;
    int li   = left_idx[ti];
    int ri   = right_idx[ti];
    float lh = h_buf[(long)li * H + j];
    float rh = h_buf[(long)ri * H + j];

    float ii = sigmoidf_(ai  + bui[j]);
    float oo = sigmoidf_(ao  + buo[j]);
    float uu = fmaxf    (au  + buu[j], 0.f);
    float f1 = sigmoidf_(af1 + bf1[j]);
    float f2 = sigmoidf_(af2 + bf2[j]);
    float c  = ii * uu + f1 * lh + f2 * rh;
    float h  = oo * fmaxf(c, 0.f);
    h_buf[(long)node * H + j] = h;
}

// ---------------- final projection ----------------
__global__ __launch_bounds__(256) void proj_kernel(
    const float* __restrict__ h_buf, const float* __restrict__ Wp,
    const float* __restrict__ bp, float* __restrict__ out, int total)
{
    int t = blockIdx.x * 256 + threadIdx.x;
    if (t >= total) return;
    int node = t / 5;
    int cls  = t - node * 5;
    const float4* hr = (const float4*)(h_buf + (long)node * H);
    const float4* wr = (const float4*)(Wp + (long)cls * H);
    float acc = 0.f;
#pragma unroll 8
    for (int k = 0; k < H / 4; ++k) {
        float4 a = hr[k], b = wr[k];
        acc += a.x * b.x + a.y * b.y + a.z * b.z + a.w * b.w;
    }
    out[t] = acc + bp[cls];
}

extern "C" void kernel_launch(void* const* d_in, const int* in_sizes, int n_in,
                              void* d_out, int out_size, void* d_ws, size_t ws_size,
                              hipStream_t stream)
{
    const int*   word_ids  = (const int*)  d_in[0];
    const int*   left_idx  = (const int*)  d_in[1];
    const int*   right_idx = (const int*)  d_in[2];
    const float* emb       = (const float*)d_in[3];
    const float* Wi  = (const float*)d_in[4];  const float* bi  = (const float*)d_in[5];
    const float* Wo  = (const float*)d_in[6];  const float* bo  = (const float*)d_in[7];
    const float* Wu  = (const float*)d_in[8];  const float* bu  = (const float*)d_in[9];
    const float* Ui  = (const float*)d_in[10]; const float* bui = (const float*)d_in[11];
    const float* Uo  = (const float*)d_in[12]; const float* buo = (const float*)d_in[13];
    const float* Uu  = (const float*)d_in[14]; const float* buu = (const float*)d_in[15];
    const float* Uf1 = (const float*)d_in[16]; const float* bf1 = (const float*)d_in[17];
    const float* Uf2 = (const float*)d_in[18]; const float* bf2 = (const float*)d_in[19];
    const float* Wp  = (const float*)d_in[20]; const float* bp  = (const float*)d_in[21];

    const int n_leaves   = in_sizes[0];
    const int n_internal = in_sizes[1];
    const int n_nodes    = n_leaves + n_internal;

    // workspace layout (floats):
    //   h_buf [n_nodes][256]
    //   W4    [4][512][256]      (internal-node weights, k-major)
    //   W3    [3][256][256]      (leaf weights, k-major)
    //   part  [chunk_cap][KTILES][4][256]
    float* ws    = (float*)d_ws;
    float* h_buf = ws;
    float* W4    = h_buf + (long)n_nodes * H;
    float* W3    = W4 + 4L * 512 * H;
    float* part  = W3 + 3L * 256 * H;
    (void)n_in; (void)out_size;

    long fixed_f = (long)n_nodes * H + 4L * 512 * H + 3L * 256 * H;
    long avail_f = (long)(ws_size / 4) - fixed_f;
    long per_node_f = (long)KTILES * 4 * H;            // 16384 floats per node
    int chunk_cap = (int)(avail_f / per_node_f);
    if (chunk_cap > 256) chunk_cap = 256;
    if (chunk_cap < 1)   chunk_cap = 1;

    // 1) pack weights: 524288 + 196608 = 720896 elements / 256 = 2816 blocks
    pack_weights_kernel<<<2816, 256, 0, stream>>>(Wi, Wo, Wu, Ui, Uo, Uu, Uf1, Uf2, W4);

    // 2) leaves
    constexpr int LPB = 8;
    leaf_kernel<LPB><<<n_leaves / LPB, 256, 0, stream>>>(
        word_ids, emb, W3, bi, bo, bu, h_buf);

    // 3) internal levels
    constexpr int NCH = 16;
    int frontier = n_leaves;
    int level_start = n_leaves;
    while (frontier > 1) {
        int cnt = frontier >> 1;
        for (int base = 0; base < cnt; base += chunk_cap) {
            int chunk = (cnt - base < chunk_cap) ? (cnt - base) : chunk_cap;
            dim3 gridA(KTILES, (chunk + NCH - 1) / NCH);
            level_partial_kernel<NCH><<<gridA, 256, 0, stream>>>(
                left_idx, right_idx, W4, h_buf, part,
                level_start, base, chunk, n_leaves);
            level_reduce_kernel<<<chunk, 256, 0, stream>>>(
                left_idx, right_idx, part,
                bui, buo, buu, bf1, bf2, h_buf,
                level_start, base, n_leaves);
        }
        level_start += cnt;
        frontier = cnt + (frontier & 1);
    }

    // 4) projection
    int total = n_nodes * 5;
    proj_kernel<<<(total + 255) / 256, 256, 0, stream>>>(h_buf, Wp, bp, (float*)d_out, total);
}